// Round 4
// baseline (28400.531 us; speedup 1.0000x reference)
//
#include <hip/hip_runtime.h>
#include <hip/hip_bf16.h>

// Problem: B=8, N=4096, C=256, c4=64. All fp32. P = B*N = 32768 points.
//
//  x0  = relu(feature @ conv0_w^T + b)            [P,64]
//  idx1 = knn12(x0);  EC1: h1=relu(u1[j]+v1[i]), h2=relu(h1@W2^T+b2), max_k -> x1 [P,256]
//  x1c = relu(x1 @ conv1_w^T + b)                 [P,64]
//  idx2 = knn8(x1c);  EC2: x2 = sum_k relu(u2[j]+v2[i])  [P,256]
//  decoder: 256->128->64->1 (all relu)
//
// u/v decomposition: W=[A|B]: edge(o) = x_j.A[o] + x_i.(B[o]-A[o]) = u[j][o] + v[i][o]

#define PTS_TOTAL 32768
#define NPTS 4096
#define NBATCH 8

// ---------------------------------------------------------------- prep weights
__global__ void prep_kernel(const float* __restrict__ w1, const float* __restrict__ b1,
                            const float* __restrict__ w2,
                            const float* __restrict__ ew, const float* __restrict__ eb,
                            float* __restrict__ wuv1, float* __restrict__ buv1,
                            float* __restrict__ wuv2, float* __restrict__ buv2,
                            float* __restrict__ w2t) {
  int tid = blockIdx.x * 256 + threadIdx.x;
  if (tid < 512 * 64) {
    int o = tid / 64, c = tid % 64;
    int orow = o & 255;
    float a  = w1[orow * 128 + c];
    float bb = w1[orow * 128 + 64 + c];
    wuv1[tid] = (o < 256) ? a : (bb - a);
    float a2  = ew[orow * 128 + c];
    float b2p = ew[orow * 128 + 64 + c];
    wuv2[tid] = (o < 256) ? a2 : (b2p - a2);
  }
  if (tid < 512) {
    buv1[tid] = (tid < 256) ? 0.f : b1[tid - 256];
    buv2[tid] = (tid < 256) ? 0.f : eb[tid - 256];
  }
  if (tid < 65536) {
    int o = tid / 256, c = tid % 256;
    w2t[c * 256 + o] = w2[o * 256 + c];
  }
}

// ---------------------------------------------------------------- generic fp32 GEMM
template<bool RELU>
__global__ __launch_bounds__(256) void gemm_rowmajor(
    const float* __restrict__ A, const float* __restrict__ W,
    const float* __restrict__ bias, float* __restrict__ Cmat,
    int M, int K, int Cout) {
  __shared__ __align__(16) float As[32][68];
  __shared__ __align__(16) float Bs[32][68];
  int m0 = blockIdx.x * 64;
  int n0 = blockIdx.y * 64;
  int tid = threadIdx.x;
  int tx = tid & 15, ty = tid >> 4;
  float acc[4][4] = {};
  for (int k0 = 0; k0 < K; k0 += 32) {
#pragma unroll
    for (int i = 0; i < 2; ++i) {
      int rr = (tid >> 3) + 32 * i;
      int cc = (tid & 7) * 4;
      float4 va = *(const float4*)&A[(size_t)(m0 + rr) * K + k0 + cc];
      float4 vb = *(const float4*)&W[(size_t)(n0 + rr) * K + k0 + cc];
      As[cc + 0][rr] = va.x; As[cc + 1][rr] = va.y; As[cc + 2][rr] = va.z; As[cc + 3][rr] = va.w;
      Bs[cc + 0][rr] = vb.x; Bs[cc + 1][rr] = vb.y; Bs[cc + 2][rr] = vb.z; Bs[cc + 3][rr] = vb.w;
    }
    __syncthreads();
#pragma unroll 8
    for (int k = 0; k < 32; ++k) {
      float4 a4 = *(const float4*)&As[k][ty * 4];
      float4 b4 = *(const float4*)&Bs[k][tx * 4];
      float a[4] = {a4.x, a4.y, a4.z, a4.w};
      float b[4] = {b4.x, b4.y, b4.z, b4.w};
#pragma unroll
      for (int ii = 0; ii < 4; ++ii)
#pragma unroll
        for (int jj = 0; jj < 4; ++jj)
          acc[ii][jj] += a[ii] * b[jj];
    }
    __syncthreads();
  }
  float4 bias4 = *(const float4*)&bias[n0 + tx * 4];
  float bv[4] = {bias4.x, bias4.y, bias4.z, bias4.w};
#pragma unroll
  for (int ii = 0; ii < 4; ++ii) {
    int m = m0 + ty * 4 + ii;
    float4 v4;
    float* vp = (float*)&v4;
#pragma unroll
    for (int jj = 0; jj < 4; ++jj) {
      float v = acc[ii][jj] + bv[jj];
      if (RELU) v = fmaxf(v, 0.f);
      vp[jj] = v;
    }
    *(float4*)&Cmat[(size_t)m * Cout + n0 + tx * 4] = v4;
  }
}

// ---------------------------------------------------------------- squared norms (C=64)
__global__ void sqnorm64(const float* __restrict__ X, float* __restrict__ xx) {
  int p = blockIdx.x * 4 + (threadIdx.x >> 6);
  int lane = threadIdx.x & 63;
  float v = X[(size_t)p * 64 + lane];
  float s = v * v;
#pragma unroll
  for (int off = 32; off >= 1; off >>= 1) s += __shfl_xor(s, off);
  if (lane == 0) xx[p] = s;
}

// ---------------------------------------------------------------- knn v4
// thread = (row, ssel): 1 row x 16 m per tile; acc in registers (no Dbuf).
// top-K list fully STATIC-indexed (registers, not scratch): sorted insert with
// unrolled compare-exchange bubble. Ties need no index compare: per-thread gi
// is monotonic, so strict < == reference's lowest-index-wins.
template<int KN>
__global__ __launch_bounds__(256, 4) void knn_kernel(
    const float* __restrict__ X,   // [B][N][64]
    const float* __restrict__ XX,  // [B][N]
    float* __restrict__ outD,      // [2][P][KN]
    int* __restrict__ outI) {      // [2][P][KN]
  __shared__ __align__(16) float smem[16 * 67 * 4 * 2 + 64];
  float4* As4 = (float4*)smem;              // [16 c4][67 pad] rows plain
  float4* Bs4 = ((float4*)smem) + 16 * 67;  // [16 c4][67 pad] m swizzled
  float* xxs = smem + 16 * 67 * 4 * 2;      // [64]
  int tid = threadIdx.x;
  int tx = tid & 15, ty = tid >> 4;         // staging map
  int row = tid >> 2, ssel = tid & 3;       // compute map
  int b = blockIdx.z;
  int split = blockIdx.y;
  int q0 = blockIdx.x * 64;
  int mbase = split * (NPTS / 2);
  const int NT = (NPTS / 2) / 64;
  const float* Xb = X + (size_t)b * NPTS * 64;
  const float* XXb = XX + (size_t)b * NPTS;
  // stage A once: As4[c4][row]
  {
    float4 va[4];
#pragma unroll
    for (int i = 0; i < 4; ++i)
      va[i] = *(const float4*)&Xb[(size_t)(q0 + ty + 16 * i) * 64 + tx * 4];
#pragma unroll
    for (int i = 0; i < 4; ++i)
      As4[tx * 67 + ty + 16 * i] = va[i];
  }
  float bd[KN];
  int bi[KN];
#pragma unroll
  for (int t = 0; t < KN; ++t) { bd[t] = 1e30f; bi[t] = 0x7fffffff; }
  // prefetch tile 0
  float4 pre[4];
  float prex;
#pragma unroll
  for (int i = 0; i < 4; ++i)
    pre[i] = *(const float4*)&Xb[(size_t)(mbase + ty + 16 * i) * 64 + tx * 4];
  prex = XXb[mbase + (tid & 63)];

  for (int t = 0; t < NT; ++t) {
    int m0 = mbase + t * 64;
    // write staged tile: m = ty+16i -> m_phys = ty*4 + i
#pragma unroll
    for (int i = 0; i < 4; ++i)
      Bs4[tx * 67 + ty * 4 + i] = pre[i];
    if (tid < 64) xxs[tid] = prex;
    // prefetch next tile into regs (hidden under GEMM+select)
    if (t + 1 < NT) {
      int m1 = m0 + 64;
#pragma unroll
      for (int i = 0; i < 4; ++i)
        pre[i] = *(const float4*)&Xb[(size_t)(m1 + ty + 16 * i) * 64 + tx * 4];
      prex = XXb[m1 + (tid & 63)];
    }
    __syncthreads();
    // GEMM: acc[mm] = dot(x_q, x_m), m = ssel*16+mm -> m_phys = mm*4 + ssel
    float acc[16] = {};
#pragma unroll
    for (int cc = 0; cc < 16; ++cc) {
      float4 a4 = As4[cc * 67 + row];
#pragma unroll
      for (int mm = 0; mm < 16; ++mm) {
        float4 b4 = Bs4[cc * 67 + mm * 4 + ssel];
        acc[mm] += a4.x * b4.x;
        acc[mm] += a4.y * b4.y;
        acc[mm] += a4.z * b4.z;
        acc[mm] += a4.w * b4.w;
      }
    }
    // select: d = xx[m] - 2*dot; sorted-insert, static indices only.
#pragma unroll
    for (int q = 0; q < 4; ++q) {
      float4 xq = *(const float4*)&xxs[ssel * 16 + q * 4];
      float dv[4];
      dv[0] = fmaf(-2.f, acc[q * 4 + 0], xq.x);
      dv[1] = fmaf(-2.f, acc[q * 4 + 1], xq.y);
      dv[2] = fmaf(-2.f, acc[q * 4 + 2], xq.z);
      dv[3] = fmaf(-2.f, acc[q * 4 + 3], xq.w);
      int gib = m0 + ssel * 16 + q * 4;
#pragma unroll
      for (int j = 0; j < 4; ++j) {
        float d = dv[j];
        if (d < bd[KN - 1]) {           // strict: tie -> keep earlier (smaller gi)
          bd[KN - 1] = d;
          bi[KN - 1] = gib + j;
#pragma unroll
          for (int t2 = KN - 1; t2 > 0; --t2) {
            bool sw = bd[t2] < bd[t2 - 1];
            float lo = fminf(bd[t2], bd[t2 - 1]);
            float hi = fmaxf(bd[t2], bd[t2 - 1]);
            int blo = sw ? bi[t2] : bi[t2 - 1];
            int bhi = sw ? bi[t2 - 1] : bi[t2];
            bd[t2 - 1] = lo; bd[t2] = hi;
            bi[t2 - 1] = blo; bi[t2] = bhi;
          }
        }
      }
    }
    __syncthreads();
  }
  // merge 4 per-row lists (lists already sorted; alias smem, all tile reads done)
  const int S = 4 * KN + 1;
  float* cd = smem;
  int* ci = (int*)(smem + 64 * S);
#pragma unroll
  for (int t = 0; t < KN; ++t) {
    cd[row * S + ssel * KN + t] = bd[t];
    ci[row * S + ssel * KN + t] = bi[t];
  }
  __syncthreads();
  if (ssel == 0) {
    int p0 = 0, p1 = 0, p2 = 0, p3 = 0;
    const float* cdr = cd + row * S;
    const int* cir = ci + row * S;
    size_t pg = (size_t)b * NPTS + q0 + row;
    float* oD = outD + ((size_t)split * PTS_TOTAL + pg) * KN;
    int* oI = outI + ((size_t)split * PTS_TOTAL + pg) * KN;
    for (int r = 0; r < KN; ++r) {
      float d0 = cdr[0 * KN + p0], d1 = cdr[1 * KN + p1];
      float d2 = cdr[2 * KN + p2], d3 = cdr[3 * KN + p3];
      int i0 = cir[0 * KN + p0], i1 = cir[1 * KN + p1];
      int i2 = cir[2 * KN + p2], i3 = cir[3 * KN + p3];
      int sel = 0; float bdd = d0; int bii = i0;
      if (d1 < bdd || (d1 == bdd && i1 < bii)) { sel = 1; bdd = d1; bii = i1; }
      if (d2 < bdd || (d2 == bdd && i2 < bii)) { sel = 2; bdd = d2; bii = i2; }
      if (d3 < bdd || (d3 == bdd && i3 < bii)) { sel = 3; bdd = d3; bii = i3; }
      oD[r] = bdd; oI[r] = bii;
      if (sel == 0) ++p0; else if (sel == 1) ++p1; else if (sel == 2) ++p2; else ++p3;
    }
  }
}

// ---------------------------------------------------------------- merge 2 split lists
template<int KN>
__global__ void merge_splits_kernel(const float* __restrict__ D, const int* __restrict__ I,
                                    int* __restrict__ IDX) {
  int p = blockIdx.x * 256 + threadIdx.x;
  const float* d0 = D + (size_t)p * KN;
  const float* d1 = D + ((size_t)PTS_TOTAL + p) * KN;
  const int* i0 = I + (size_t)p * KN;
  const int* i1 = I + ((size_t)PTS_TOTAL + p) * KN;
  int* op = IDX + (size_t)p * KN;
  int a = 0, c = 0;
#pragma unroll
  for (int r = 0; r < KN; ++r) {
    float da = d0[a], dc = d1[c];
    int ia = i0[a], ic = i1[c];
    bool t = (dc < da) || (dc == da && ic < ia);
    op[r] = t ? ic : ia;
    if (t) ++c; else ++a;
  }
}

// ---------------------------------------------------------------- EC1: gather + MLP2 + max
__global__ __launch_bounds__(256) void ec1_kernel(
    const float* __restrict__ UV,   // [P][512] (u | v+b1)
    const int* __restrict__ IDX,    // [P][12]
    const float* __restrict__ W2T,  // [256 c][256 o]
    const float* __restrict__ B2,   // [256]
    float* __restrict__ OUT) {      // [P][256]
  __shared__ __align__(16) float h1[4][12][256];
  int wave = threadIdx.x >> 6;
  int lane = threadIdx.x & 63;
  int p = blockIdx.x * 4 + wave;
  int bbase = (p >> 12) << 12;  // batch start point
  const float* uvb = UV + (size_t)bbase * 512;
  const float* vrow = UV + (size_t)p * 512 + 256;
  float4 v4 = *(const float4*)&vrow[lane * 4];
#pragma unroll
  for (int k = 0; k < 12; ++k) {
    int jn = IDX[p * 12 + k];
    const float* urow = uvb + (size_t)jn * 512;
    float4 u4 = *(const float4*)&urow[lane * 4];
    float4 h;
    h.x = fmaxf(u4.x + v4.x, 0.f); h.y = fmaxf(u4.y + v4.y, 0.f);
    h.z = fmaxf(u4.z + v4.z, 0.f); h.w = fmaxf(u4.w + v4.w, 0.f);
    *(float4*)&h1[wave][k][lane * 4] = h;
  }
  __syncthreads();
  float acc[12][4] = {};
  const float* wbase = W2T + lane * 4;
  for (int c0 = 0; c0 < 256; c0 += 4) {
    float4 w0 = *(const float4*)&wbase[(size_t)(c0 + 0) * 256];
    float4 w1 = *(const float4*)&wbase[(size_t)(c0 + 1) * 256];
    float4 w2 = *(const float4*)&wbase[(size_t)(c0 + 2) * 256];
    float4 w3 = *(const float4*)&wbase[(size_t)(c0 + 3) * 256];
#pragma unroll
    for (int k = 0; k < 12; ++k) {
      float4 h = *(const float4*)&h1[wave][k][c0];  // wave-uniform broadcast
      acc[k][0] += h.x * w0.x + h.y * w1.x + h.z * w2.x + h.w * w3.x;
      acc[k][1] += h.x * w0.y + h.y * w1.y + h.z * w2.y + h.w * w3.y;
      acc[k][2] += h.x * w0.z + h.y * w1.z + h.z * w2.z + h.w * w3.z;
      acc[k][3] += h.x * w0.w + h.y * w1.w + h.z * w2.w + h.w * w3.w;
    }
  }
  float4 b4 = *(const float4*)&B2[lane * 4];
  float m0v = acc[0][0], m1v = acc[0][1], m2v = acc[0][2], m3v = acc[0][3];
#pragma unroll
  for (int k = 1; k < 12; ++k) {
    m0v = fmaxf(m0v, acc[k][0]); m1v = fmaxf(m1v, acc[k][1]);
    m2v = fmaxf(m2v, acc[k][2]); m3v = fmaxf(m3v, acc[k][3]);
  }
  float4 o4;
  o4.x = fmaxf(m0v + b4.x, 0.f); o4.y = fmaxf(m1v + b4.y, 0.f);
  o4.z = fmaxf(m2v + b4.z, 0.f); o4.w = fmaxf(m3v + b4.w, 0.f);
  *(float4*)&OUT[(size_t)p * 256 + lane * 4] = o4;
}

// ---------------------------------------------------------------- EC2: gather + relu + sum
__global__ __launch_bounds__(256) void ec2_kernel(
    const float* __restrict__ UV, const int* __restrict__ IDX,
    float* __restrict__ OUT) {
  int wave = threadIdx.x >> 6;
  int lane = threadIdx.x & 63;
  int p = blockIdx.x * 4 + wave;
  int bbase = (p >> 12) << 12;
  const float* uvb = UV + (size_t)bbase * 512;
  const float* vrow = UV + (size_t)p * 512 + 256;
  float4 v4 = *(const float4*)&vrow[lane * 4];
  float4 a4 = {0.f, 0.f, 0.f, 0.f};
#pragma unroll
  for (int k = 0; k < 8; ++k) {
    int jn = IDX[p * 8 + k];
    const float* urow = uvb + (size_t)jn * 512;
    float4 u4 = *(const float4*)&urow[lane * 4];
    a4.x += fmaxf(u4.x + v4.x, 0.f); a4.y += fmaxf(u4.y + v4.y, 0.f);
    a4.z += fmaxf(u4.z + v4.z, 0.f); a4.w += fmaxf(u4.w + v4.w, 0.f);
  }
  *(float4*)&OUT[(size_t)p * 256 + lane * 4] = a4;
}

// ---------------------------------------------------------------- final 64->1
__global__ void final_kernel(const float* __restrict__ X, const float* __restrict__ W,
                             const float* __restrict__ Bb, float* __restrict__ OUT) {
  int p = blockIdx.x * 4 + (threadIdx.x >> 6);
  int lane = threadIdx.x & 63;
  float v = X[(size_t)p * 64 + lane] * W[lane];
#pragma unroll
  for (int off = 32; off >= 1; off >>= 1) v += __shfl_xor(v, off);
  if (lane == 0) OUT[p] = fmaxf(v + Bb[0], 0.f);
}

// ---------------------------------------------------------------- launch
extern "C" void kernel_launch(void* const* d_in, const int* in_sizes, int n_in,
                              void* d_out, int out_size, void* d_ws, size_t ws_size,
                              hipStream_t stream) {
  const float* feature = (const float*)d_in[0];
  const float* conv0_w = (const float*)d_in[1];
  const float* conv0_b = (const float*)d_in[2];
  const float* ec1_w1  = (const float*)d_in[3];
  const float* ec1_b1  = (const float*)d_in[4];
  const float* ec1_w2  = (const float*)d_in[5];
  const float* ec1_b2  = (const float*)d_in[6];
  const float* conv1_w = (const float*)d_in[7];
  const float* conv1_b = (const float*)d_in[8];
  const float* ec2_w   = (const float*)d_in[9];
  const float* ec2_b   = (const float*)d_in[10];
  const float* dec1_w  = (const float*)d_in[11];
  const float* dec1_b  = (const float*)d_in[12];
  const float* dec2_w  = (const float*)d_in[13];
  const float* dec2_b  = (const float*)d_in[14];
  const float* out_w   = (const float*)d_in[15];
  const float* out_b   = (const float*)d_in[16];
  float* out = (float*)d_out;

  char* ws = (char*)d_ws;
  float* wuv1 = (float*)(ws + 0);
  float* buv1 = (float*)(ws + 131072);
  float* wuv2 = (float*)(ws + 133120);
  float* buv2 = (float*)(ws + 264192);
  float* w2t  = (float*)(ws + 266240);
  float* xx   = (float*)(ws + 528384);
  int*   idx  = (int*)  (ws + 659456);
  float* x0   = (float*)(ws + 2232320);   // x0 -> x1c -> xd2
  float* uv   = (float*)(ws + 10620928);  // knnD/knnI -> uv1 -> knnD/knnI -> uv2 -> xd1
  float* x1   = (float*)(ws + 77729792);  // x1 -> x2

  // knn scratch lives inside the (currently dead) uv region
  float* knnD = (float*)(ws + 10620928);
  int*   knnI = (int*)(ws + 10620928 + 3145728);

  const int P = PTS_TOTAL;

  prep_kernel<<<256, 256, 0, stream>>>(ec1_w1, ec1_b1, ec1_w2, ec2_w, ec2_b,
                                       wuv1, buv1, wuv2, buv2, w2t);
  gemm_rowmajor<true><<<dim3(P / 64, 1), 256, 0, stream>>>(feature, conv0_w, conv0_b, x0, P, 256, 64);
  sqnorm64<<<P / 4, 256, 0, stream>>>(x0, xx);
  knn_kernel<12><<<dim3(NPTS / 64, 2, NBATCH), 256, 0, stream>>>(x0, xx, knnD, knnI);
  merge_splits_kernel<12><<<P / 256, 256, 0, stream>>>(knnD, knnI, idx);
  gemm_rowmajor<false><<<dim3(P / 64, 8), 256, 0, stream>>>(x0, wuv1, buv1, uv, P, 64, 512);
  ec1_kernel<<<P / 4, 256, 0, stream>>>(uv, idx, w2t, ec1_b2, x1);
  gemm_rowmajor<true><<<dim3(P / 64, 1), 256, 0, stream>>>(x1, conv1_w, conv1_b, x0, P, 256, 64);
  sqnorm64<<<P / 4, 256, 0, stream>>>(x0, xx);
  knn_kernel<8><<<dim3(NPTS / 64, 2, NBATCH), 256, 0, stream>>>(x0, xx, knnD, knnI);
  merge_splits_kernel<8><<<P / 256, 256, 0, stream>>>(knnD, knnI, idx);
  gemm_rowmajor<false><<<dim3(P / 64, 8), 256, 0, stream>>>(x0, wuv2, buv2, uv, P, 64, 512);
  ec2_kernel<<<P / 4, 256, 0, stream>>>(uv, idx, x1);
  float* xd1 = uv;
  gemm_rowmajor<true><<<dim3(P / 64, 2), 256, 0, stream>>>(x1, dec1_w, dec1_b, xd1, P, 256, 128);
  float* xd2 = x0;
  gemm_rowmajor<true><<<dim3(P / 64, 1), 256, 0, stream>>>(xd1, dec2_w, dec2_b, xd2, P, 128, 64);
  final_kernel<<<P / 4, 256, 0, stream>>>(xd2, out_w, out_b, out);
}

// Round 5
// 3743.386 us; speedup vs baseline: 7.5869x; 7.5869x over previous
//
#include <hip/hip_runtime.h>
#include <hip/hip_bf16.h>

// Problem: B=8, N=4096, C=256, c4=64. All fp32. P = B*N = 32768 points.
//
//  x0  = relu(feature @ conv0_w^T + b)            [P,64]
//  idx1 = knn12(x0);  EC1: h1=relu(u1[j]+v1[i]), h2=relu(h1@W2^T+b2), max_k -> x1 [P,256]
//  x1c = relu(x1 @ conv1_w^T + b)                 [P,64]
//  idx2 = knn8(x1c);  EC2: x2 = sum_k relu(u2[j]+v2[i])  [P,256]
//  decoder: 256->128->64->1 (all relu)
//
// u/v decomposition: W=[A|B]: edge(o) = x_j.A[o] + x_i.(B[o]-A[o]) = u[j][o] + v[i][o]

#define PTS_TOTAL 32768
#define NPTS 4096
#define NBATCH 8

// ---------------------------------------------------------------- prep weights
__global__ void prep_kernel(const float* __restrict__ w1, const float* __restrict__ b1,
                            const float* __restrict__ w2,
                            const float* __restrict__ ew, const float* __restrict__ eb,
                            float* __restrict__ wuv1, float* __restrict__ buv1,
                            float* __restrict__ wuv2, float* __restrict__ buv2,
                            float* __restrict__ w2t) {
  int tid = blockIdx.x * 256 + threadIdx.x;
  if (tid < 512 * 64) {
    int o = tid / 64, c = tid % 64;
    int orow = o & 255;
    float a  = w1[orow * 128 + c];
    float bb = w1[orow * 128 + 64 + c];
    wuv1[tid] = (o < 256) ? a : (bb - a);
    float a2  = ew[orow * 128 + c];
    float b2p = ew[orow * 128 + 64 + c];
    wuv2[tid] = (o < 256) ? a2 : (b2p - a2);
  }
  if (tid < 512) {
    buv1[tid] = (tid < 256) ? 0.f : b1[tid - 256];
    buv2[tid] = (tid < 256) ? 0.f : eb[tid - 256];
  }
  if (tid < 65536) {
    int o = tid / 256, c = tid % 256;
    w2t[c * 256 + o] = w2[o * 256 + c];
  }
}

// ---------------------------------------------------------------- generic fp32 GEMM
template<bool RELU>
__global__ __launch_bounds__(256) void gemm_rowmajor(
    const float* __restrict__ A, const float* __restrict__ W,
    const float* __restrict__ bias, float* __restrict__ Cmat,
    int M, int K, int Cout) {
  __shared__ __align__(16) float As[32][68];
  __shared__ __align__(16) float Bs[32][68];
  int m0 = blockIdx.x * 64;
  int n0 = blockIdx.y * 64;
  int tid = threadIdx.x;
  int tx = tid & 15, ty = tid >> 4;
  float acc[4][4] = {};
  for (int k0 = 0; k0 < K; k0 += 32) {
#pragma unroll
    for (int i = 0; i < 2; ++i) {
      int rr = (tid >> 3) + 32 * i;
      int cc = (tid & 7) * 4;
      float4 va = *(const float4*)&A[(size_t)(m0 + rr) * K + k0 + cc];
      float4 vb = *(const float4*)&W[(size_t)(n0 + rr) * K + k0 + cc];
      As[cc + 0][rr] = va.x; As[cc + 1][rr] = va.y; As[cc + 2][rr] = va.z; As[cc + 3][rr] = va.w;
      Bs[cc + 0][rr] = vb.x; Bs[cc + 1][rr] = vb.y; Bs[cc + 2][rr] = vb.z; Bs[cc + 3][rr] = vb.w;
    }
    __syncthreads();
#pragma unroll 8
    for (int k = 0; k < 32; ++k) {
      float4 a4 = *(const float4*)&As[k][ty * 4];
      float4 b4 = *(const float4*)&Bs[k][tx * 4];
      float a[4] = {a4.x, a4.y, a4.z, a4.w};
      float b[4] = {b4.x, b4.y, b4.z, b4.w};
#pragma unroll
      for (int ii = 0; ii < 4; ++ii)
#pragma unroll
        for (int jj = 0; jj < 4; ++jj)
          acc[ii][jj] += a[ii] * b[jj];
    }
    __syncthreads();
  }
  float4 bias4 = *(const float4*)&bias[n0 + tx * 4];
  float bv[4] = {bias4.x, bias4.y, bias4.z, bias4.w};
#pragma unroll
  for (int ii = 0; ii < 4; ++ii) {
    int m = m0 + ty * 4 + ii;
    float4 v4;
    float* vp = (float*)&v4;
#pragma unroll
    for (int jj = 0; jj < 4; ++jj) {
      float v = acc[ii][jj] + bv[jj];
      if (RELU) v = fmaxf(v, 0.f);
      vp[jj] = v;
    }
    *(float4*)&Cmat[(size_t)m * Cout + n0 + tx * 4] = v4;
  }
}

// ---------------------------------------------------------------- squared norms (C=64)
__global__ void sqnorm64(const float* __restrict__ X, float* __restrict__ xx) {
  int p = blockIdx.x * 4 + (threadIdx.x >> 6);
  int lane = threadIdx.x & 63;
  float v = X[(size_t)p * 64 + lane];
  float s = v * v;
#pragma unroll
  for (int off = 32; off >= 1; off >>= 1) s += __shfl_xor(s, off);
  if (lane == 0) xx[p] = s;
}

// ---------------------------------------------------------------- knn v5
// = r3 structure (proven non-spilling pressure profile) + static sorted-insert.
// thread = (row, ssel): 1 row x 16 m per tile; acc in registers (no Dbuf).
// Plain __launch_bounds__(256) and cc-loop unroll 2: keep register pressure in
// the regime where SROA promotes bd[]/bi[] (r2 evidence: VGPR=120, no scratch).
// Quad min-gate vs bd[KN-1] cuts insert-branch entry ~4x.
template<int KN>
__global__ __launch_bounds__(256) void knn_kernel(
    const float* __restrict__ X,   // [B][N][64]
    const float* __restrict__ XX,  // [B][N]
    float* __restrict__ outD,      // [2][P][KN]
    int* __restrict__ outI) {      // [2][P][KN]
  __shared__ __align__(16) float smem[16 * 67 * 4 * 2 + 64];
  float4* As4 = (float4*)smem;              // [16 c4][67 pad] rows plain
  float4* Bs4 = ((float4*)smem) + 16 * 67;  // [16 c4][67 pad] m swizzled
  float* xxs = smem + 16 * 67 * 4 * 2;      // [64]
  int tid = threadIdx.x;
  int tx = tid & 15, ty = tid >> 4;         // staging map
  int row = tid >> 2, ssel = tid & 3;       // compute map
  int b = blockIdx.z;
  int split = blockIdx.y;
  int q0 = blockIdx.x * 64;
  int mbase = split * (NPTS / 2);
  const int NT = (NPTS / 2) / 64;
  const float* Xb = X + (size_t)b * NPTS * 64;
  const float* XXb = XX + (size_t)b * NPTS;
  // stage A once: As4[c4][row]
  {
    float4 va[4];
#pragma unroll
    for (int i = 0; i < 4; ++i)
      va[i] = *(const float4*)&Xb[(size_t)(q0 + ty + 16 * i) * 64 + tx * 4];
#pragma unroll
    for (int i = 0; i < 4; ++i)
      As4[tx * 67 + ty + 16 * i] = va[i];
  }
  float bd[KN];
  int bi[KN];
#pragma unroll
  for (int t = 0; t < KN; ++t) { bd[t] = 1e30f; bi[t] = 0x7fffffff; }
  // prefetch tile 0
  float4 pre[4];
  float prex;
#pragma unroll
  for (int i = 0; i < 4; ++i)
    pre[i] = *(const float4*)&Xb[(size_t)(mbase + ty + 16 * i) * 64 + tx * 4];
  prex = XXb[mbase + (tid & 63)];

  for (int t = 0; t < NT; ++t) {
    int m0 = mbase + t * 64;
    // write staged tile: m = ty+16i -> m_phys = ty*4 + i
#pragma unroll
    for (int i = 0; i < 4; ++i)
      Bs4[tx * 67 + ty * 4 + i] = pre[i];
    if (tid < 64) xxs[tid] = prex;
    // prefetch next tile into regs (hidden under GEMM+select)
    if (t + 1 < NT) {
      int m1 = m0 + 64;
#pragma unroll
      for (int i = 0; i < 4; ++i)
        pre[i] = *(const float4*)&Xb[(size_t)(m1 + ty + 16 * i) * 64 + tx * 4];
      prex = XXb[m1 + (tid & 63)];
    }
    __syncthreads();
    // GEMM: acc[mm] = dot(x_q, x_m), m = ssel*16+mm -> m_phys = mm*4 + ssel
    float acc[16] = {};
#pragma unroll 2
    for (int cc = 0; cc < 16; ++cc) {
      float4 a4 = As4[cc * 67 + row];
#pragma unroll
      for (int mm = 0; mm < 16; ++mm) {
        float4 b4 = Bs4[cc * 67 + mm * 4 + ssel];
        acc[mm] += a4.x * b4.x;
        acc[mm] += a4.y * b4.y;
        acc[mm] += a4.z * b4.z;
        acc[mm] += a4.w * b4.w;
      }
    }
    // select: d = xx[m] - 2*dot; quad-gated static sorted-insert.
#pragma unroll
    for (int q = 0; q < 4; ++q) {
      float4 xq = *(const float4*)&xxs[ssel * 16 + q * 4];
      float dv[4];
      dv[0] = fmaf(-2.f, acc[q * 4 + 0], xq.x);
      dv[1] = fmaf(-2.f, acc[q * 4 + 1], xq.y);
      dv[2] = fmaf(-2.f, acc[q * 4 + 2], xq.z);
      dv[3] = fmaf(-2.f, acc[q * 4 + 3], xq.w);
      float mn = fminf(fminf(dv[0], dv[1]), fminf(dv[2], dv[3]));
      if (mn < bd[KN - 1]) {
        int gib = m0 + ssel * 16 + q * 4;
#pragma unroll
        for (int j = 0; j < 4; ++j) {
          float d = dv[j];
          if (d < bd[KN - 1]) {         // strict: tie -> keep earlier (smaller gi)
            bd[KN - 1] = d;
            bi[KN - 1] = gib + j;
#pragma unroll
            for (int t2 = KN - 1; t2 > 0; --t2) {
              bool sw = bd[t2] < bd[t2 - 1];
              float lo = fminf(bd[t2], bd[t2 - 1]);
              float hi = fmaxf(bd[t2], bd[t2 - 1]);
              int blo = sw ? bi[t2] : bi[t2 - 1];
              int bhi = sw ? bi[t2 - 1] : bi[t2];
              bd[t2 - 1] = lo; bd[t2] = hi;
              bi[t2 - 1] = blo; bi[t2] = bhi;
            }
          }
        }
      }
    }
    __syncthreads();
  }
  // merge 4 per-row lists (lists already sorted; alias smem, all tile reads done)
  const int S = 4 * KN + 1;
  float* cd = smem;
  int* ci = (int*)(smem + 64 * S);
#pragma unroll
  for (int t = 0; t < KN; ++t) {
    cd[row * S + ssel * KN + t] = bd[t];
    ci[row * S + ssel * KN + t] = bi[t];
  }
  __syncthreads();
  if (ssel == 0) {
    int p0 = 0, p1 = 0, p2 = 0, p3 = 0;
    const float* cdr = cd + row * S;
    const int* cir = ci + row * S;
    size_t pg = (size_t)b * NPTS + q0 + row;
    float* oD = outD + ((size_t)split * PTS_TOTAL + pg) * KN;
    int* oI = outI + ((size_t)split * PTS_TOTAL + pg) * KN;
    for (int r = 0; r < KN; ++r) {
      float d0 = cdr[0 * KN + p0], d1 = cdr[1 * KN + p1];
      float d2 = cdr[2 * KN + p2], d3 = cdr[3 * KN + p3];
      int i0 = cir[0 * KN + p0], i1 = cir[1 * KN + p1];
      int i2 = cir[2 * KN + p2], i3 = cir[3 * KN + p3];
      int sel = 0; float bdd = d0; int bii = i0;
      if (d1 < bdd || (d1 == bdd && i1 < bii)) { sel = 1; bdd = d1; bii = i1; }
      if (d2 < bdd || (d2 == bdd && i2 < bii)) { sel = 2; bdd = d2; bii = i2; }
      if (d3 < bdd || (d3 == bdd && i3 < bii)) { sel = 3; bdd = d3; bii = i3; }
      oD[r] = bdd; oI[r] = bii;
      if (sel == 0) ++p0; else if (sel == 1) ++p1; else if (sel == 2) ++p2; else ++p3;
    }
  }
}

// ---------------------------------------------------------------- merge 2 split lists
template<int KN>
__global__ void merge_splits_kernel(const float* __restrict__ D, const int* __restrict__ I,
                                    int* __restrict__ IDX) {
  int p = blockIdx.x * 256 + threadIdx.x;
  const float* d0 = D + (size_t)p * KN;
  const float* d1 = D + ((size_t)PTS_TOTAL + p) * KN;
  const int* i0 = I + (size_t)p * KN;
  const int* i1 = I + ((size_t)PTS_TOTAL + p) * KN;
  int* op = IDX + (size_t)p * KN;
  int a = 0, c = 0;
#pragma unroll
  for (int r = 0; r < KN; ++r) {
    float da = d0[a], dc = d1[c];
    int ia = i0[a], ic = i1[c];
    bool t = (dc < da) || (dc == da && ic < ia);
    op[r] = t ? ic : ia;
    if (t) ++c; else ++a;
  }
}

// ---------------------------------------------------------------- EC1: gather + MLP2 + max
__global__ __launch_bounds__(256) void ec1_kernel(
    const float* __restrict__ UV,   // [P][512] (u | v+b1)
    const int* __restrict__ IDX,    // [P][12]
    const float* __restrict__ W2T,  // [256 c][256 o]
    const float* __restrict__ B2,   // [256]
    float* __restrict__ OUT) {      // [P][256]
  __shared__ __align__(16) float h1[4][12][256];
  int wave = threadIdx.x >> 6;
  int lane = threadIdx.x & 63;
  int p = blockIdx.x * 4 + wave;
  int bbase = (p >> 12) << 12;  // batch start point
  const float* uvb = UV + (size_t)bbase * 512;
  const float* vrow = UV + (size_t)p * 512 + 256;
  float4 v4 = *(const float4*)&vrow[lane * 4];
#pragma unroll
  for (int k = 0; k < 12; ++k) {
    int jn = IDX[p * 12 + k];
    const float* urow = uvb + (size_t)jn * 512;
    float4 u4 = *(const float4*)&urow[lane * 4];
    float4 h;
    h.x = fmaxf(u4.x + v4.x, 0.f); h.y = fmaxf(u4.y + v4.y, 0.f);
    h.z = fmaxf(u4.z + v4.z, 0.f); h.w = fmaxf(u4.w + v4.w, 0.f);
    *(float4*)&h1[wave][k][lane * 4] = h;
  }
  __syncthreads();
  float acc[12][4] = {};
  const float* wbase = W2T + lane * 4;
  for (int c0 = 0; c0 < 256; c0 += 4) {
    float4 w0 = *(const float4*)&wbase[(size_t)(c0 + 0) * 256];
    float4 w1 = *(const float4*)&wbase[(size_t)(c0 + 1) * 256];
    float4 w2 = *(const float4*)&wbase[(size_t)(c0 + 2) * 256];
    float4 w3 = *(const float4*)&wbase[(size_t)(c0 + 3) * 256];
#pragma unroll
    for (int k = 0; k < 12; ++k) {
      float4 h = *(const float4*)&h1[wave][k][c0];  // wave-uniform broadcast
      acc[k][0] += h.x * w0.x + h.y * w1.x + h.z * w2.x + h.w * w3.x;
      acc[k][1] += h.x * w0.y + h.y * w1.y + h.z * w2.y + h.w * w3.y;
      acc[k][2] += h.x * w0.z + h.y * w1.z + h.z * w2.z + h.w * w3.z;
      acc[k][3] += h.x * w0.w + h.y * w1.w + h.z * w2.w + h.w * w3.w;
    }
  }
  float4 b4 = *(const float4*)&B2[lane * 4];
  float m0v = acc[0][0], m1v = acc[0][1], m2v = acc[0][2], m3v = acc[0][3];
#pragma unroll
  for (int k = 1; k < 12; ++k) {
    m0v = fmaxf(m0v, acc[k][0]); m1v = fmaxf(m1v, acc[k][1]);
    m2v = fmaxf(m2v, acc[k][2]); m3v = fmaxf(m3v, acc[k][3]);
  }
  float4 o4;
  o4.x = fmaxf(m0v + b4.x, 0.f); o4.y = fmaxf(m1v + b4.y, 0.f);
  o4.z = fmaxf(m2v + b4.z, 0.f); o4.w = fmaxf(m3v + b4.w, 0.f);
  *(float4*)&OUT[(size_t)p * 256 + lane * 4] = o4;
}

// ---------------------------------------------------------------- EC2: gather + relu + sum
__global__ __launch_bounds__(256) void ec2_kernel(
    const float* __restrict__ UV, const int* __restrict__ IDX,
    float* __restrict__ OUT) {
  int wave = threadIdx.x >> 6;
  int lane = threadIdx.x & 63;
  int p = blockIdx.x * 4 + wave;
  int bbase = (p >> 12) << 12;
  const float* uvb = UV + (size_t)bbase * 512;
  const float* vrow = UV + (size_t)p * 512 + 256;
  float4 v4 = *(const float4*)&vrow[lane * 4];
  float4 a4 = {0.f, 0.f, 0.f, 0.f};
#pragma unroll
  for (int k = 0; k < 8; ++k) {
    int jn = IDX[p * 8 + k];
    const float* urow = uvb + (size_t)jn * 512;
    float4 u4 = *(const float4*)&urow[lane * 4];
    a4.x += fmaxf(u4.x + v4.x, 0.f); a4.y += fmaxf(u4.y + v4.y, 0.f);
    a4.z += fmaxf(u4.z + v4.z, 0.f); a4.w += fmaxf(u4.w + v4.w, 0.f);
  }
  *(float4*)&OUT[(size_t)p * 256 + lane * 4] = a4;
}

// ---------------------------------------------------------------- final 64->1
__global__ void final_kernel(const float* __restrict__ X, const float* __restrict__ W,
                             const float* __restrict__ Bb, float* __restrict__ OUT) {
  int p = blockIdx.x * 4 + (threadIdx.x >> 6);
  int lane = threadIdx.x & 63;
  float v = X[(size_t)p * 64 + lane] * W[lane];
#pragma unroll
  for (int off = 32; off >= 1; off >>= 1) v += __shfl_xor(v, off);
  if (lane == 0) OUT[p] = fmaxf(v + Bb[0], 0.f);
}

// ---------------------------------------------------------------- launch
extern "C" void kernel_launch(void* const* d_in, const int* in_sizes, int n_in,
                              void* d_out, int out_size, void* d_ws, size_t ws_size,
                              hipStream_t stream) {
  const float* feature = (const float*)d_in[0];
  const float* conv0_w = (const float*)d_in[1];
  const float* conv0_b = (const float*)d_in[2];
  const float* ec1_w1  = (const float*)d_in[3];
  const float* ec1_b1  = (const float*)d_in[4];
  const float* ec1_w2  = (const float*)d_in[5];
  const float* ec1_b2  = (const float*)d_in[6];
  const float* conv1_w = (const float*)d_in[7];
  const float* conv1_b = (const float*)d_in[8];
  const float* ec2_w   = (const float*)d_in[9];
  const float* ec2_b   = (const float*)d_in[10];
  const float* dec1_w  = (const float*)d_in[11];
  const float* dec1_b  = (const float*)d_in[12];
  const float* dec2_w  = (const float*)d_in[13];
  const float* dec2_b  = (const float*)d_in[14];
  const float* out_w   = (const float*)d_in[15];
  const float* out_b   = (const float*)d_in[16];
  float* out = (float*)d_out;

  char* ws = (char*)d_ws;
  float* wuv1 = (float*)(ws + 0);
  float* buv1 = (float*)(ws + 131072);
  float* wuv2 = (float*)(ws + 133120);
  float* buv2 = (float*)(ws + 264192);
  float* w2t  = (float*)(ws + 266240);
  float* xx   = (float*)(ws + 528384);
  int*   idx  = (int*)  (ws + 659456);
  float* x0   = (float*)(ws + 2232320);   // x0 -> x1c -> xd2
  float* uv   = (float*)(ws + 10620928);  // knnD/knnI -> uv1 -> knnD/knnI -> uv2 -> xd1
  float* x1   = (float*)(ws + 77729792);  // x1 -> x2

  // knn scratch lives inside the (currently dead) uv region
  float* knnD = (float*)(ws + 10620928);
  int*   knnI = (int*)(ws + 10620928 + 3145728);

  const int P = PTS_TOTAL;

  prep_kernel<<<256, 256, 0, stream>>>(ec1_w1, ec1_b1, ec1_w2, ec2_w, ec2_b,
                                       wuv1, buv1, wuv2, buv2, w2t);
  gemm_rowmajor<true><<<dim3(P / 64, 1), 256, 0, stream>>>(feature, conv0_w, conv0_b, x0, P, 256, 64);
  sqnorm64<<<P / 4, 256, 0, stream>>>(x0, xx);
  knn_kernel<12><<<dim3(NPTS / 64, 2, NBATCH), 256, 0, stream>>>(x0, xx, knnD, knnI);
  merge_splits_kernel<12><<<P / 256, 256, 0, stream>>>(knnD, knnI, idx);
  gemm_rowmajor<false><<<dim3(P / 64, 8), 256, 0, stream>>>(x0, wuv1, buv1, uv, P, 64, 512);
  ec1_kernel<<<P / 4, 256, 0, stream>>>(uv, idx, w2t, ec1_b2, x1);
  gemm_rowmajor<true><<<dim3(P / 64, 1), 256, 0, stream>>>(x1, conv1_w, conv1_b, x0, P, 256, 64);
  sqnorm64<<<P / 4, 256, 0, stream>>>(x0, xx);
  knn_kernel<8><<<dim3(NPTS / 64, 2, NBATCH), 256, 0, stream>>>(x0, xx, knnD, knnI);
  merge_splits_kernel<8><<<P / 256, 256, 0, stream>>>(knnD, knnI, idx);
  gemm_rowmajor<false><<<dim3(P / 64, 8), 256, 0, stream>>>(x0, wuv2, buv2, uv, P, 64, 512);
  ec2_kernel<<<P / 4, 256, 0, stream>>>(uv, idx, x1);
  float* xd1 = uv;
  gemm_rowmajor<true><<<dim3(P / 64, 2), 256, 0, stream>>>(x1, dec1_w, dec1_b, xd1, P, 256, 128);
  float* xd2 = x0;
  gemm_rowmajor<true><<<dim3(P / 64, 1), 256, 0, stream>>>(xd1, dec2_w, dec2_b, xd2, P, 128, 64);
  final_kernel<<<P / 4, 256, 0, stream>>>(xd2, out_w, out_b, out);
}

// Round 6
// 1971.413 us; speedup vs baseline: 14.4062x; 1.8988x over previous
//
#include <hip/hip_runtime.h>
#include <hip/hip_bf16.h>

// Problem: B=8, N=4096, C=256, c4=64. All fp32. P = B*N = 32768 points.
//
//  x0  = relu(feature @ conv0_w^T + b)            [P,64]
//  idx1 = knn12(x0);  EC1: h1=relu(u1[j]+v1[i]), h2=relu(h1@W2^T+b2), max_k -> x1 [P,256]
//  x1c = relu(x1 @ conv1_w^T + b)                 [P,64]
//  idx2 = knn8(x1c);  EC2: x2 = sum_k relu(u2[j]+v2[i])  [P,256]
//  decoder: 256->128->64->1 (all relu)
//
// u/v decomposition: W=[A|B]: edge(o) = x_j.A[o] + x_i.(B[o]-A[o]) = u[j][o] + v[i][o]

#define PTS_TOTAL 32768
#define NPTS 4096
#define NBATCH 8

// ---------------------------------------------------------------- prep weights
__global__ void prep_kernel(const float* __restrict__ w1, const float* __restrict__ b1,
                            const float* __restrict__ w2,
                            const float* __restrict__ ew, const float* __restrict__ eb,
                            float* __restrict__ wuv1, float* __restrict__ buv1,
                            float* __restrict__ wuv2, float* __restrict__ buv2,
                            float* __restrict__ w2t) {
  int tid = blockIdx.x * 256 + threadIdx.x;
  if (tid < 512 * 64) {
    int o = tid / 64, c = tid % 64;
    int orow = o & 255;
    float a  = w1[orow * 128 + c];
    float bb = w1[orow * 128 + 64 + c];
    wuv1[tid] = (o < 256) ? a : (bb - a);
    float a2  = ew[orow * 128 + c];
    float b2p = ew[orow * 128 + 64 + c];
    wuv2[tid] = (o < 256) ? a2 : (b2p - a2);
  }
  if (tid < 512) {
    buv1[tid] = (tid < 256) ? 0.f : b1[tid - 256];
    buv2[tid] = (tid < 256) ? 0.f : eb[tid - 256];
  }
  if (tid < 65536) {
    int o = tid / 256, c = tid % 256;
    w2t[c * 256 + o] = w2[o * 256 + c];
  }
}

// ---------------------------------------------------------------- generic fp32 GEMM
template<bool RELU>
__global__ __launch_bounds__(256) void gemm_rowmajor(
    const float* __restrict__ A, const float* __restrict__ W,
    const float* __restrict__ bias, float* __restrict__ Cmat,
    int M, int K, int Cout) {
  __shared__ __align__(16) float As[32][68];
  __shared__ __align__(16) float Bs[32][68];
  int m0 = blockIdx.x * 64;
  int n0 = blockIdx.y * 64;
  int tid = threadIdx.x;
  int tx = tid & 15, ty = tid >> 4;
  float acc[4][4] = {};
  for (int k0 = 0; k0 < K; k0 += 32) {
#pragma unroll
    for (int i = 0; i < 2; ++i) {
      int rr = (tid >> 3) + 32 * i;
      int cc = (tid & 7) * 4;
      float4 va = *(const float4*)&A[(size_t)(m0 + rr) * K + k0 + cc];
      float4 vb = *(const float4*)&W[(size_t)(n0 + rr) * K + k0 + cc];
      As[cc + 0][rr] = va.x; As[cc + 1][rr] = va.y; As[cc + 2][rr] = va.z; As[cc + 3][rr] = va.w;
      Bs[cc + 0][rr] = vb.x; Bs[cc + 1][rr] = vb.y; Bs[cc + 2][rr] = vb.z; Bs[cc + 3][rr] = vb.w;
    }
    __syncthreads();
#pragma unroll 8
    for (int k = 0; k < 32; ++k) {
      float4 a4 = *(const float4*)&As[k][ty * 4];
      float4 b4 = *(const float4*)&Bs[k][tx * 4];
      float a[4] = {a4.x, a4.y, a4.z, a4.w};
      float b[4] = {b4.x, b4.y, b4.z, b4.w};
#pragma unroll
      for (int ii = 0; ii < 4; ++ii)
#pragma unroll
        for (int jj = 0; jj < 4; ++jj)
          acc[ii][jj] += a[ii] * b[jj];
    }
    __syncthreads();
  }
  float4 bias4 = *(const float4*)&bias[n0 + tx * 4];
  float bv[4] = {bias4.x, bias4.y, bias4.z, bias4.w};
#pragma unroll
  for (int ii = 0; ii < 4; ++ii) {
    int m = m0 + ty * 4 + ii;
    float4 v4;
    float* vp = (float*)&v4;
#pragma unroll
    for (int jj = 0; jj < 4; ++jj) {
      float v = acc[ii][jj] + bv[jj];
      if (RELU) v = fmaxf(v, 0.f);
      vp[jj] = v;
    }
    *(float4*)&Cmat[(size_t)m * Cout + n0 + tx * 4] = v4;
  }
}

// ---------------------------------------------------------------- squared norms (C=64)
__global__ void sqnorm64(const float* __restrict__ X, float* __restrict__ xx) {
  int p = blockIdx.x * 4 + (threadIdx.x >> 6);
  int lane = threadIdx.x & 63;
  float v = X[(size_t)p * 64 + lane];
  float s = v * v;
#pragma unroll
  for (int off = 32; off >= 1; off >>= 1) s += __shfl_xor(s, off);
  if (lane == 0) xx[p] = s;
}

// ---------------------------------------------------------------- knn v6
// Top-K list in NAMED SCALAR REGISTERS (td0..td11/ti0..ti11) — promotion no
// longer depends on unroll heuristics (r3/r4/r5 all demoted bd[]/bi[] arrays
// to scratch: VGPR=52, 120-230 MB scratch traffic). Insert = gated chain of
// named compare-exchanges. Strict < everywhere: per-thread gi is monotonic,
// so ties keep the earlier (smaller) index == reference semantics.
#define ORD(a, b)                                                   \
  { bool sw_ = td##b < td##a;                                       \
    float lo_ = fminf(td##a, td##b), hi_ = fmaxf(td##a, td##b);     \
    int il_ = sw_ ? ti##b : ti##a, ih_ = sw_ ? ti##a : ti##b;       \
    td##a = lo_; td##b = hi_; ti##a = il_; ti##b = ih_; }

#define INS(d, gi)                                                  \
  if (KN == 12) {                                                   \
    if ((d) < td11) {                                               \
      td11 = (d); ti11 = (gi);                                      \
      ORD(10,11) ORD(9,10) ORD(8,9) ORD(7,8) ORD(6,7) ORD(5,6)      \
      ORD(4,5) ORD(3,4) ORD(2,3) ORD(1,2) ORD(0,1)                  \
    }                                                               \
  } else {                                                          \
    if ((d) < td7) {                                                \
      td7 = (d); ti7 = (gi);                                        \
      ORD(6,7) ORD(5,6) ORD(4,5) ORD(3,4) ORD(2,3) ORD(1,2) ORD(0,1)\
    }                                                               \
  }

template<int KN>
__global__ __launch_bounds__(256) void knn_kernel(
    const float* __restrict__ X,   // [B][N][64]
    const float* __restrict__ XX,  // [B][N]
    float* __restrict__ outD,      // [2][P][KN]
    int* __restrict__ outI) {      // [2][P][KN]
  __shared__ __align__(16) float smem[16 * 67 * 4 * 2 + 64];
  float4* As4 = (float4*)smem;              // [16 c4][67 pad] rows plain
  float4* Bs4 = ((float4*)smem) + 16 * 67;  // [16 c4][67 pad] m swizzled
  float* xxs = smem + 16 * 67 * 4 * 2;      // [64]
  int tid = threadIdx.x;
  int tx = tid & 15, ty = tid >> 4;         // staging map
  int row = tid >> 2, ssel = tid & 3;       // compute map
  int b = blockIdx.z;
  int split = blockIdx.y;
  int q0 = blockIdx.x * 64;
  int mbase = split * (NPTS / 2);
  const int NT = (NPTS / 2) / 64;
  const float* Xb = X + (size_t)b * NPTS * 64;
  const float* XXb = XX + (size_t)b * NPTS;
  // stage A once: As4[c4][row]
  {
    float4 va[4];
#pragma unroll
    for (int i = 0; i < 4; ++i)
      va[i] = *(const float4*)&Xb[(size_t)(q0 + ty + 16 * i) * 64 + tx * 4];
#pragma unroll
    for (int i = 0; i < 4; ++i)
      As4[tx * 67 + ty + 16 * i] = va[i];
  }
  // top-K list: named scalar registers
  float td0 = 1e30f, td1 = 1e30f, td2 = 1e30f, td3 = 1e30f,
        td4 = 1e30f, td5 = 1e30f, td6 = 1e30f, td7 = 1e30f,
        td8 = 1e30f, td9 = 1e30f, td10 = 1e30f, td11 = 1e30f;
  int ti0 = 0x7fffffff, ti1 = 0x7fffffff, ti2 = 0x7fffffff, ti3 = 0x7fffffff,
      ti4 = 0x7fffffff, ti5 = 0x7fffffff, ti6 = 0x7fffffff, ti7 = 0x7fffffff,
      ti8 = 0x7fffffff, ti9 = 0x7fffffff, ti10 = 0x7fffffff, ti11 = 0x7fffffff;
  // prefetch tile 0
  float4 pre[4];
  float prex;
#pragma unroll
  for (int i = 0; i < 4; ++i)
    pre[i] = *(const float4*)&Xb[(size_t)(mbase + ty + 16 * i) * 64 + tx * 4];
  prex = XXb[mbase + (tid & 63)];

  for (int t = 0; t < NT; ++t) {
    int m0 = mbase + t * 64;
    // write staged tile: m = ty+16i -> m_phys = ty*4 + i
#pragma unroll
    for (int i = 0; i < 4; ++i)
      Bs4[tx * 67 + ty * 4 + i] = pre[i];
    if (tid < 64) xxs[tid] = prex;
    // prefetch next tile into regs (hidden under GEMM+select)
    if (t + 1 < NT) {
      int m1 = m0 + 64;
#pragma unroll
      for (int i = 0; i < 4; ++i)
        pre[i] = *(const float4*)&Xb[(size_t)(m1 + ty + 16 * i) * 64 + tx * 4];
      prex = XXb[m1 + (tid & 63)];
    }
    __syncthreads();
    // GEMM: acc[mm] = dot(x_q, x_m), m = ssel*16+mm -> m_phys = mm*4 + ssel
    float acc[16] = {};
#pragma unroll 2
    for (int cc = 0; cc < 16; ++cc) {
      float4 a4 = As4[cc * 67 + row];
#pragma unroll
      for (int mm = 0; mm < 16; ++mm) {
        float4 b4 = Bs4[cc * 67 + mm * 4 + ssel];
        acc[mm] += a4.x * b4.x;
        acc[mm] += a4.y * b4.y;
        acc[mm] += a4.z * b4.z;
        acc[mm] += a4.w * b4.w;
      }
    }
    // select: d = xx[m] - 2*dot; quad-gated named-register sorted insert.
    float worst;
#pragma unroll
    for (int q = 0; q < 4; ++q) {
      float4 xq = *(const float4*)&xxs[ssel * 16 + q * 4];
      float dv0 = fmaf(-2.f, acc[q * 4 + 0], xq.x);
      float dv1 = fmaf(-2.f, acc[q * 4 + 1], xq.y);
      float dv2 = fmaf(-2.f, acc[q * 4 + 2], xq.z);
      float dv3 = fmaf(-2.f, acc[q * 4 + 3], xq.w);
      float mn = fminf(fminf(dv0, dv1), fminf(dv2, dv3));
      worst = (KN == 12) ? td11 : td7;
      if (mn < worst) {
        int gib = m0 + ssel * 16 + q * 4;
        INS(dv0, gib + 0)
        INS(dv1, gib + 1)
        INS(dv2, gib + 2)
        INS(dv3, gib + 3)
      }
    }
    __syncthreads();
  }
  // dump named lists to LDS; merge 4 per-row lists (alias smem; reads done)
  const int S = 4 * KN + 1;
  float* cd = smem;
  int* ci = (int*)(smem + 64 * S);
  {
    float* cdr = cd + row * S + ssel * KN;
    int* cir = ci + row * S + ssel * KN;
    cdr[0] = td0; cdr[1] = td1; cdr[2] = td2; cdr[3] = td3;
    cdr[4] = td4; cdr[5] = td5; cdr[6] = td6; cdr[7] = td7;
    cir[0] = ti0; cir[1] = ti1; cir[2] = ti2; cir[3] = ti3;
    cir[4] = ti4; cir[5] = ti5; cir[6] = ti6; cir[7] = ti7;
    if (KN == 12) {
      cdr[8] = td8; cdr[9] = td9; cdr[10] = td10; cdr[11] = td11;
      cir[8] = ti8; cir[9] = ti9; cir[10] = ti10; cir[11] = ti11;
    }
  }
  __syncthreads();
  if (ssel == 0) {
    int p0 = 0, p1 = 0, p2 = 0, p3 = 0;
    const float* cdr = cd + row * S;
    const int* cir = ci + row * S;
    size_t pg = (size_t)b * NPTS + q0 + row;
    float* oD = outD + ((size_t)split * PTS_TOTAL + pg) * KN;
    int* oI = outI + ((size_t)split * PTS_TOTAL + pg) * KN;
    for (int r = 0; r < KN; ++r) {
      float d0 = cdr[0 * KN + p0], d1 = cdr[1 * KN + p1];
      float d2 = cdr[2 * KN + p2], d3 = cdr[3 * KN + p3];
      int i0 = cir[0 * KN + p0], i1 = cir[1 * KN + p1];
      int i2 = cir[2 * KN + p2], i3 = cir[3 * KN + p3];
      int sel = 0; float bdd = d0; int bii = i0;
      if (d1 < bdd || (d1 == bdd && i1 < bii)) { sel = 1; bdd = d1; bii = i1; }
      if (d2 < bdd || (d2 == bdd && i2 < bii)) { sel = 2; bdd = d2; bii = i2; }
      if (d3 < bdd || (d3 == bdd && i3 < bii)) { sel = 3; bdd = d3; bii = i3; }
      oD[r] = bdd; oI[r] = bii;
      if (sel == 0) ++p0; else if (sel == 1) ++p1; else if (sel == 2) ++p2; else ++p3;
    }
  }
}
#undef INS
#undef ORD

// ---------------------------------------------------------------- merge 2 split lists
template<int KN>
__global__ void merge_splits_kernel(const float* __restrict__ D, const int* __restrict__ I,
                                    int* __restrict__ IDX) {
  int p = blockIdx.x * 256 + threadIdx.x;
  const float* d0 = D + (size_t)p * KN;
  const float* d1 = D + ((size_t)PTS_TOTAL + p) * KN;
  const int* i0 = I + (size_t)p * KN;
  const int* i1 = I + ((size_t)PTS_TOTAL + p) * KN;
  int* op = IDX + (size_t)p * KN;
  int a = 0, c = 0;
#pragma unroll
  for (int r = 0; r < KN; ++r) {
    float da = d0[a], dc = d1[c];
    int ia = i0[a], ic = i1[c];
    bool t = (dc < da) || (dc == da && ic < ia);
    op[r] = t ? ic : ia;
    if (t) ++c; else ++a;
  }
}

// ---------------------------------------------------------------- EC1: gather + MLP2 + max
__global__ __launch_bounds__(256) void ec1_kernel(
    const float* __restrict__ UV,   // [P][512] (u | v+b1)
    const int* __restrict__ IDX,    // [P][12]
    const float* __restrict__ W2T,  // [256 c][256 o]
    const float* __restrict__ B2,   // [256]
    float* __restrict__ OUT) {      // [P][256]
  __shared__ __align__(16) float h1[4][12][256];
  int wave = threadIdx.x >> 6;
  int lane = threadIdx.x & 63;
  int p = blockIdx.x * 4 + wave;
  int bbase = (p >> 12) << 12;  // batch start point
  const float* uvb = UV + (size_t)bbase * 512;
  const float* vrow = UV + (size_t)p * 512 + 256;
  float4 v4 = *(const float4*)&vrow[lane * 4];
#pragma unroll
  for (int k = 0; k < 12; ++k) {
    int jn = IDX[p * 12 + k];
    const float* urow = uvb + (size_t)jn * 512;
    float4 u4 = *(const float4*)&urow[lane * 4];
    float4 h;
    h.x = fmaxf(u4.x + v4.x, 0.f); h.y = fmaxf(u4.y + v4.y, 0.f);
    h.z = fmaxf(u4.z + v4.z, 0.f); h.w = fmaxf(u4.w + v4.w, 0.f);
    *(float4*)&h1[wave][k][lane * 4] = h;
  }
  __syncthreads();
  float acc[12][4] = {};
  const float* wbase = W2T + lane * 4;
  for (int c0 = 0; c0 < 256; c0 += 4) {
    float4 w0 = *(const float4*)&wbase[(size_t)(c0 + 0) * 256];
    float4 w1 = *(const float4*)&wbase[(size_t)(c0 + 1) * 256];
    float4 w2 = *(const float4*)&wbase[(size_t)(c0 + 2) * 256];
    float4 w3 = *(const float4*)&wbase[(size_t)(c0 + 3) * 256];
#pragma unroll
    for (int k = 0; k < 12; ++k) {
      float4 h = *(const float4*)&h1[wave][k][c0];  // wave-uniform broadcast
      acc[k][0] += h.x * w0.x + h.y * w1.x + h.z * w2.x + h.w * w3.x;
      acc[k][1] += h.x * w0.y + h.y * w1.y + h.z * w2.y + h.w * w3.y;
      acc[k][2] += h.x * w0.z + h.y * w1.z + h.z * w2.z + h.w * w3.z;
      acc[k][3] += h.x * w0.w + h.y * w1.w + h.z * w2.w + h.w * w3.w;
    }
  }
  float4 b4 = *(const float4*)&B2[lane * 4];
  float m0v = acc[0][0], m1v = acc[0][1], m2v = acc[0][2], m3v = acc[0][3];
#pragma unroll
  for (int k = 1; k < 12; ++k) {
    m0v = fmaxf(m0v, acc[k][0]); m1v = fmaxf(m1v, acc[k][1]);
    m2v = fmaxf(m2v, acc[k][2]); m3v = fmaxf(m3v, acc[k][3]);
  }
  float4 o4;
  o4.x = fmaxf(m0v + b4.x, 0.f); o4.y = fmaxf(m1v + b4.y, 0.f);
  o4.z = fmaxf(m2v + b4.z, 0.f); o4.w = fmaxf(m3v + b4.w, 0.f);
  *(float4*)&OUT[(size_t)p * 256 + lane * 4] = o4;
}

// ---------------------------------------------------------------- EC2: gather + relu + sum
__global__ __launch_bounds__(256) void ec2_kernel(
    const float* __restrict__ UV, const int* __restrict__ IDX,
    float* __restrict__ OUT) {
  int wave = threadIdx.x >> 6;
  int lane = threadIdx.x & 63;
  int p = blockIdx.x * 4 + wave;
  int bbase = (p >> 12) << 12;
  const float* uvb = UV + (size_t)bbase * 512;
  const float* vrow = UV + (size_t)p * 512 + 256;
  float4 v4 = *(const float4*)&vrow[lane * 4];
  float4 a4 = {0.f, 0.f, 0.f, 0.f};
#pragma unroll
  for (int k = 0; k < 8; ++k) {
    int jn = IDX[p * 8 + k];
    const float* urow = uvb + (size_t)jn * 512;
    float4 u4 = *(const float4*)&urow[lane * 4];
    a4.x += fmaxf(u4.x + v4.x, 0.f); a4.y += fmaxf(u4.y + v4.y, 0.f);
    a4.z += fmaxf(u4.z + v4.z, 0.f); a4.w += fmaxf(u4.w + v4.w, 0.f);
  }
  *(float4*)&OUT[(size_t)p * 256 + lane * 4] = a4;
}

// ---------------------------------------------------------------- final 64->1
__global__ void final_kernel(const float* __restrict__ X, const float* __restrict__ W,
                             const float* __restrict__ Bb, float* __restrict__ OUT) {
  int p = blockIdx.x * 4 + (threadIdx.x >> 6);
  int lane = threadIdx.x & 63;
  float v = X[(size_t)p * 64 + lane] * W[lane];
#pragma unroll
  for (int off = 32; off >= 1; off >>= 1) v += __shfl_xor(v, off);
  if (lane == 0) OUT[p] = fmaxf(v + Bb[0], 0.f);
}

// ---------------------------------------------------------------- launch
extern "C" void kernel_launch(void* const* d_in, const int* in_sizes, int n_in,
                              void* d_out, int out_size, void* d_ws, size_t ws_size,
                              hipStream_t stream) {
  const float* feature = (const float*)d_in[0];
  const float* conv0_w = (const float*)d_in[1];
  const float* conv0_b = (const float*)d_in[2];
  const float* ec1_w1  = (const float*)d_in[3];
  const float* ec1_b1  = (const float*)d_in[4];
  const float* ec1_w2  = (const float*)d_in[5];
  const float* ec1_b2  = (const float*)d_in[6];
  const float* conv1_w = (const float*)d_in[7];
  const float* conv1_b = (const float*)d_in[8];
  const float* ec2_w   = (const float*)d_in[9];
  const float* ec2_b   = (const float*)d_in[10];
  const float* dec1_w  = (const float*)d_in[11];
  const float* dec1_b  = (const float*)d_in[12];
  const float* dec2_w  = (const float*)d_in[13];
  const float* dec2_b  = (const float*)d_in[14];
  const float* out_w   = (const float*)d_in[15];
  const float* out_b   = (const float*)d_in[16];
  float* out = (float*)d_out;

  char* ws = (char*)d_ws;
  float* wuv1 = (float*)(ws + 0);
  float* buv1 = (float*)(ws + 131072);
  float* wuv2 = (float*)(ws + 133120);
  float* buv2 = (float*)(ws + 264192);
  float* w2t  = (float*)(ws + 266240);
  float* xx   = (float*)(ws + 528384);
  int*   idx  = (int*)  (ws + 659456);
  float* x0   = (float*)(ws + 2232320);   // x0 -> x1c -> xd2
  float* uv   = (float*)(ws + 10620928);  // knnD/knnI -> uv1 -> knnD/knnI -> uv2 -> xd1
  float* x1   = (float*)(ws + 77729792);  // x1 -> x2

  // knn scratch lives inside the (currently dead) uv region
  float* knnD = (float*)(ws + 10620928);
  int*   knnI = (int*)(ws + 10620928 + 3145728);

  const int P = PTS_TOTAL;

  prep_kernel<<<256, 256, 0, stream>>>(ec1_w1, ec1_b1, ec1_w2, ec2_w, ec2_b,
                                       wuv1, buv1, wuv2, buv2, w2t);
  gemm_rowmajor<true><<<dim3(P / 64, 1), 256, 0, stream>>>(feature, conv0_w, conv0_b, x0, P, 256, 64);
  sqnorm64<<<P / 4, 256, 0, stream>>>(x0, xx);
  knn_kernel<12><<<dim3(NPTS / 64, 2, NBATCH), 256, 0, stream>>>(x0, xx, knnD, knnI);
  merge_splits_kernel<12><<<P / 256, 256, 0, stream>>>(knnD, knnI, idx);
  gemm_rowmajor<false><<<dim3(P / 64, 8), 256, 0, stream>>>(x0, wuv1, buv1, uv, P, 64, 512);
  ec1_kernel<<<P / 4, 256, 0, stream>>>(uv, idx, w2t, ec1_b2, x1);
  gemm_rowmajor<true><<<dim3(P / 64, 1), 256, 0, stream>>>(x1, conv1_w, conv1_b, x0, P, 256, 64);
  sqnorm64<<<P / 4, 256, 0, stream>>>(x0, xx);
  knn_kernel<8><<<dim3(NPTS / 64, 2, NBATCH), 256, 0, stream>>>(x0, xx, knnD, knnI);
  merge_splits_kernel<8><<<P / 256, 256, 0, stream>>>(knnD, knnI, idx);
  gemm_rowmajor<false><<<dim3(P / 64, 8), 256, 0, stream>>>(x0, wuv2, buv2, uv, P, 64, 512);
  ec2_kernel<<<P / 4, 256, 0, stream>>>(uv, idx, x1);
  float* xd1 = uv;
  gemm_rowmajor<true><<<dim3(P / 64, 2), 256, 0, stream>>>(x1, dec1_w, dec1_b, xd1, P, 256, 128);
  float* xd2 = x0;
  gemm_rowmajor<true><<<dim3(P / 64, 1), 256, 0, stream>>>(xd1, dec2_w, dec2_b, xd2, P, 128, 64);
  final_kernel<<<P / 4, 256, 0, stream>>>(xd2, out_w, out_b, out);
}